// Round 4
// baseline (18.237 us; speedup 1.0000x reference)
//
#include <hip/hip_runtime.h>

// Separable 5x5 median (median of row-medians), zero-padded, f32.
// Thread = 4 consecutive columns (float4) x strip of TH=8 rows.
// Horizontal halo via __shfl from neighbor lanes; rolling register windows
// for row-medians and center pixels. Plain cacheable stores (L3 absorbs
// the 25 MB output; nontemporal stores forced HBM serialization in r3).

#define CE(a, b) { float _t = fminf(a, b); (b) = fmaxf(a, b); (a) = _t; }

__device__ __forceinline__ float med5(float a0, float a1, float a2, float a3, float a4) {
    CE(a0, a1); CE(a2, a3); CE(a0, a2); CE(a1, a3); CE(a1, a2);
    return fmaxf(a1, fminf(a4, a2));
}

__global__ __launch_bounds__(256) void median5_kernel(const float* __restrict__ in,
                                                      float* __restrict__ out) {
    constexpr int W = 512, H = 512, TH = 8;
    int idx   = blockIdx.x * blockDim.x + threadIdx.x;
    int cg    = idx & 127;            // column group (4 cols each)
    int strip = (idx >> 7) & 63;      // H / TH = 64 strips
    int bc    = idx >> 13;            // plane 0..23

    const float* p = in  + (size_t)bc * H * W;
    float*       q = out + (size_t)bc * H * W;
    const int h0 = strip * TH;
    const int w4 = cg * 4;
    const int lane = threadIdx.x & 63;
    const bool lEdge = (lane == 0);
    const bool rEdge = (lane == 63);
    const float4 z4 = make_float4(0.f, 0.f, 0.f, 0.f);

    auto rowload = [&](int ih, float4& C) -> float4 {
        if (ih < 0 || ih >= H) { C = z4; return z4; }
        const float* r = p + ih * W;
        C = *(const float4*)(r + w4);
        float lz = __shfl_up(C.z, 1);    // r[w4-2]
        float lw = __shfl_up(C.w, 1);    // r[w4-1]
        float rx = __shfl_down(C.x, 1);  // r[w4+4]
        float ry = __shfl_down(C.y, 1);  // r[w4+5]
        if (lEdge) {
            if (w4 >= 4) { lz = r[w4 - 2]; lw = r[w4 - 1]; }
            else         { lz = 0.f;       lw = 0.f; }
        }
        if (rEdge) {
            if (w4 + 4 < W) { rx = r[w4 + 4]; ry = r[w4 + 5]; }
            else            { rx = 0.f;       ry = 0.f; }
        }
        float4 m;
        m.x = med5(lz, lw, C.x, C.y, C.z);
        m.y = med5(lw, C.x, C.y, C.z, C.w);
        m.z = med5(C.x, C.y, C.z, C.w, rx);
        m.w = med5(C.y, C.z, C.w, rx, ry);
        return m;
    };

    float4 cT;
    float4 cA, cB, cC;                 // centers for rows h, h+1, h+2
    float4 m0 = rowload(h0 - 2, cT);
    float4 m1 = rowload(h0 - 1, cT);
    float4 m2 = rowload(h0,     cA);
    float4 m3 = rowload(h0 + 1, cB);

    #pragma unroll
    for (int i = 0; i < TH; ++i) {
        int h = h0 + i;
        float4 m4 = rowload(h + 2, cC);
        float4 o;
        o.x = (med5(m0.x, m1.x, m2.x, m3.x, m4.x) - cA.x) + cA.x;
        o.y = (med5(m0.y, m1.y, m2.y, m3.y, m4.y) - cA.y) + cA.y;
        o.z = (med5(m0.z, m1.z, m2.z, m3.z, m4.z) - cA.z) + cA.z;
        o.w = (med5(m0.w, m1.w, m2.w, m3.w, m4.w) - cA.w) + cA.w;
        *(float4*)(q + h * W + w4) = o;
        m0 = m1; m1 = m2; m2 = m3; m3 = m4;
        cA = cB; cB = cC;
    }
}

extern "C" void kernel_launch(void* const* d_in, const int* in_sizes, int n_in,
                              void* d_out, int out_size, void* d_ws, size_t ws_size,
                              hipStream_t stream) {
    const float* in = (const float*)d_in[0];   // [8,3,512,512] f32
    float* out = (float*)d_out;
    constexpr int W = 512, H = 512, TH = 8, BC = 24;
    int total_threads = BC * (H / TH) * (W / 4);   // 196608
    int block = 256;
    int grid = total_threads / block;              // 768
    median5_kernel<<<grid, block, 0, stream>>>(in, out);
}

// Round 5
// 15.333 us; speedup vs baseline: 1.1894x; 1.1894x over previous
//
#include <hip/hip_runtime.h>

// Separable 5x5 median (median of row-medians), zero-padded, f32.
// Thread = 4 consecutive columns (float4) x strip of TH=4 rows.
// Raw rows (center float4 + edge-lane halo scalars) prefetched one
// iteration ahead; shfl-based horizontal halo; nontemporal stores
// (proven +2.4us in r3/r4 A/B: keeps L2 read-clean).

#define CE(a, b) { float _t = fminf(a, b); (b) = fmaxf(a, b); (a) = _t; }

typedef float f32x4 __attribute__((ext_vector_type(4)));

__device__ __forceinline__ float med5(float a0, float a1, float a2, float a3, float a4) {
    CE(a0, a1); CE(a2, a3); CE(a0, a2); CE(a1, a3); CE(a1, a2);
    return fmaxf(a1, fminf(a4, a2));
}

struct Row { float4 C; float e0, e1; };

__global__ __launch_bounds__(256) void median5_kernel(const float* __restrict__ in,
                                                      float* __restrict__ out) {
    constexpr int W = 512, H = 512, TH = 4;
    int idx   = blockIdx.x * blockDim.x + threadIdx.x;
    int cg    = idx & 127;             // column group (4 cols each)
    int strip = (idx >> 7) & 127;      // H / TH = 128 strips
    int bc    = idx >> 14;             // plane 0..23

    const float* p = in  + (size_t)bc * H * W;
    float*       q = out + (size_t)bc * H * W;
    const int h0 = strip * TH;
    const int w4 = cg * 4;
    const int lane = threadIdx.x & 63;
    const bool lEdge = (lane == 0);
    const bool rEdge = (lane == 63);
    const float4 z4 = make_float4(0.f, 0.f, 0.f, 0.f);

    // All loads (center float4 + edge-lane halo scalars) happen here,
    // one iteration before consumption.
    auto rawload = [&](int ih) -> Row {
        Row r;
        if (ih < 0 || ih >= H) { r.C = z4; r.e0 = 0.f; r.e1 = 0.f; return r; }
        const float* rp = p + ih * W;
        r.C = *(const float4*)(rp + w4);
        float a = 0.f, b = 0.f;
        if (lEdge && w4 >= 4)    { a = rp[w4 - 2]; b = rp[w4 - 1]; }
        if (rEdge && w4 + 4 < W) { a = rp[w4 + 4]; b = rp[w4 + 5]; }
        r.e0 = a; r.e1 = b;
        return r;
    };

    // Pure register/DS work: shfl halo + 4 horizontal medians.
    auto rowmed = [&](const Row& rr) -> float4 {
        float4 C = rr.C;
        float lz = __shfl_up(C.z, 1);
        float lw = __shfl_up(C.w, 1);
        float rx = __shfl_down(C.x, 1);
        float ry = __shfl_down(C.y, 1);
        if (lEdge) { lz = rr.e0; lw = rr.e1; }   // e0/e1 are 0 at true image edge
        if (rEdge) { rx = rr.e0; ry = rr.e1; }
        float4 m;
        m.x = med5(lz, lw, C.x, C.y, C.z);
        m.y = med5(lw, C.x, C.y, C.z, C.w);
        m.z = med5(C.x, C.y, C.z, C.w, rx);
        m.w = med5(C.y, C.z, C.w, rx, ry);
        return m;
    };

    // Prologue: 5 raw loads issued back-to-back (ILP), then 4 row-medians.
    Row r0 = rawload(h0 - 2);
    Row r1 = rawload(h0 - 1);
    Row r2 = rawload(h0);
    Row r3 = rawload(h0 + 1);
    Row r4 = rawload(h0 + 2);
    float4 m0 = rowmed(r0);
    float4 m1 = rowmed(r1);
    float4 m2 = rowmed(r2);
    float4 m3 = rowmed(r3);

    #pragma unroll
    for (int i = 0; i < TH; ++i) {
        int h = h0 + i;
        Row rN = (i + 1 < TH) ? rawload(h + 3) : r4;  // prefetch next iter's row
        float4 m4 = rowmed(r4);                       // consumes last iter's load
        float4 cA = r2.C;                             // center row h (no reload)
        f32x4 o;
        o.x = (med5(m0.x, m1.x, m2.x, m3.x, m4.x) - cA.x) + cA.x;
        o.y = (med5(m0.y, m1.y, m2.y, m3.y, m4.y) - cA.y) + cA.y;
        o.z = (med5(m0.z, m1.z, m2.z, m3.z, m4.z) - cA.z) + cA.z;
        o.w = (med5(m0.w, m1.w, m2.w, m3.w, m4.w) - cA.w) + cA.w;
        __builtin_nontemporal_store(o, (f32x4*)(q + h * W + w4));
        m0 = m1; m1 = m2; m2 = m3; m3 = m4;
        r2 = r3; r3 = r4; r4 = rN;
    }
}

extern "C" void kernel_launch(void* const* d_in, const int* in_sizes, int n_in,
                              void* d_out, int out_size, void* d_ws, size_t ws_size,
                              hipStream_t stream) {
    const float* in = (const float*)d_in[0];   // [8,3,512,512] f32
    float* out = (float*)d_out;
    constexpr int W = 512, H = 512, TH = 4, BC = 24;
    int total_threads = BC * (H / TH) * (W / 4);   // 393216
    int block = 256;
    int grid = total_threads / block;              // 1536
    median5_kernel<<<grid, block, 0, stream>>>(in, out);
}

// Round 6
// 14.969 us; speedup vs baseline: 1.2184x; 1.0244x over previous
//
#include <hip/hip_runtime.h>

// Separable 5x5 median (median of row-medians), zero-padded, f32.
// Thread = 4 consecutive columns (float4) x strip of TH=8 rows (1.5x
// vertical read amplification vs 2x at TH=4). Raw rows prefetched one
// iteration ahead (r5's win); shfl horizontal halo; nontemporal stores
// (r3/r4 A/B: +2.4us, keeps L2 read-clean).

#define CE(a, b) { float _t = fminf(a, b); (b) = fmaxf(a, b); (a) = _t; }

typedef float f32x4 __attribute__((ext_vector_type(4)));

__device__ __forceinline__ float med5(float a0, float a1, float a2, float a3, float a4) {
    CE(a0, a1); CE(a2, a3); CE(a0, a2); CE(a1, a3); CE(a1, a2);
    return fmaxf(a1, fminf(a4, a2));
}

struct Row { float4 C; float e0, e1; };

__global__ __launch_bounds__(256) void median5_kernel(const float* __restrict__ in,
                                                      float* __restrict__ out) {
    constexpr int W = 512, H = 512, TH = 8;
    int idx   = blockIdx.x * blockDim.x + threadIdx.x;
    int cg    = idx & 127;            // column group (4 cols each)
    int strip = (idx >> 7) & 63;      // H / TH = 64 strips
    int bc    = idx >> 13;            // plane 0..23

    const float* p = in  + (size_t)bc * H * W;
    float*       q = out + (size_t)bc * H * W;
    const int h0 = strip * TH;
    const int w4 = cg * 4;
    const int lane = threadIdx.x & 63;
    const bool lEdge = (lane == 0);
    const bool rEdge = (lane == 63);
    const float4 z4 = make_float4(0.f, 0.f, 0.f, 0.f);

    // All loads (center float4 + edge-lane halo scalars) issued here,
    // one iteration before consumption.
    auto rawload = [&](int ih) -> Row {
        Row r;
        if (ih < 0 || ih >= H) { r.C = z4; r.e0 = 0.f; r.e1 = 0.f; return r; }
        const float* rp = p + ih * W;
        r.C = *(const float4*)(rp + w4);
        float a = 0.f, b = 0.f;
        if (lEdge && w4 >= 4)    { a = rp[w4 - 2]; b = rp[w4 - 1]; }
        if (rEdge && w4 + 4 < W) { a = rp[w4 + 4]; b = rp[w4 + 5]; }
        r.e0 = a; r.e1 = b;
        return r;
    };

    // Pure register/DS work: shfl halo + 4 horizontal medians.
    auto rowmed = [&](const Row& rr) -> float4 {
        float4 C = rr.C;
        float lz = __shfl_up(C.z, 1);
        float lw = __shfl_up(C.w, 1);
        float rx = __shfl_down(C.x, 1);
        float ry = __shfl_down(C.y, 1);
        if (lEdge) { lz = rr.e0; lw = rr.e1; }
        if (rEdge) { rx = rr.e0; ry = rr.e1; }
        float4 m;
        m.x = med5(lz, lw, C.x, C.y, C.z);
        m.y = med5(lw, C.x, C.y, C.z, C.w);
        m.z = med5(C.x, C.y, C.z, C.w, rx);
        m.w = med5(C.y, C.z, C.w, rx, ry);
        return m;
    };

    Row r0 = rawload(h0 - 2);
    Row r1 = rawload(h0 - 1);
    Row r2 = rawload(h0);
    Row r3 = rawload(h0 + 1);
    Row r4 = rawload(h0 + 2);
    float4 m0 = rowmed(r0);
    float4 m1 = rowmed(r1);
    float4 m2 = rowmed(r2);
    float4 m3 = rowmed(r3);

    #pragma unroll
    for (int i = 0; i < TH; ++i) {
        int h = h0 + i;
        Row rN = (i + 1 < TH) ? rawload(h + 3) : r4;  // prefetch next iter's row
        float4 m4 = rowmed(r4);                       // consumes last iter's load
        float4 cA = r2.C;                             // center row h (no reload)
        f32x4 o;
        o.x = (med5(m0.x, m1.x, m2.x, m3.x, m4.x) - cA.x) + cA.x;
        o.y = (med5(m0.y, m1.y, m2.y, m3.y, m4.y) - cA.y) + cA.y;
        o.z = (med5(m0.z, m1.z, m2.z, m3.z, m4.z) - cA.z) + cA.z;
        o.w = (med5(m0.w, m1.w, m2.w, m3.w, m4.w) - cA.w) + cA.w;
        __builtin_nontemporal_store(o, (f32x4*)(q + h * W + w4));
        m0 = m1; m1 = m2; m2 = m3; m3 = m4;
        r2 = r3; r3 = r4; r4 = rN;
    }
}

extern "C" void kernel_launch(void* const* d_in, const int* in_sizes, int n_in,
                              void* d_out, int out_size, void* d_ws, size_t ws_size,
                              hipStream_t stream) {
    const float* in = (const float*)d_in[0];   // [8,3,512,512] f32
    float* out = (float*)d_out;
    constexpr int W = 512, H = 512, TH = 8, BC = 24;
    int total_threads = BC * (H / TH) * (W / 4);   // 196608
    int block = 256;
    int grid = total_threads / block;              // 768
    median5_kernel<<<grid, block, 0, stream>>>(in, out);
}